// Round 3
// baseline (294.400 us; speedup 1.0000x reference)
//
#include <hip/hip_runtime.h>
#include <hip/hip_cooperative_groups.h>

namespace cg = cooperative_groups;

typedef unsigned short u16;
typedef unsigned int u32;
typedef __attribute__((ext_vector_type(8))) short short8;    // 8 bf16 (4 VGPRs)
typedef __attribute__((ext_vector_type(4))) float floatx4;   // 4 fp32 acc
typedef __attribute__((ext_vector_type(4))) u32 uint4v;

// Pack two fp32 -> two bf16 (RNE) in one dword: low16=bf(a), high16=bf(b).
__device__ __forceinline__ u32 pack2bf(float a, float b) {
    u32 ua = __float_as_uint(a), ub = __float_as_uint(b);
    ua += 0x7fffu + ((ua >> 16) & 1u);   // RNE
    ub += 0x7fffu + ((ub >> 16) & 1u);
    return __builtin_amdgcn_perm(ub, ua, 0x07060302);
}

// ---------------------------------------------------------------------------
// Normalize one 128x64 tile (tile id = blk: 0..99 q, 100..199 s), pack bf16,
// store to ws in MFMA-FRAGMENT ORDER:
//   elem addr(rowblk, ks, lane) = blk*8192 + (rowblk*2 + ks)*512 + lane*8
// so a GEMM fragment load is one coalesced global_load_dwordx4 (1 KB/wave).
// ---------------------------------------------------------------------------
__device__ __forceinline__ void normalize_tile(const float* __restrict__ q,
                                               const float* __restrict__ s,
                                               u16* __restrict__ ws,
                                               int blk, int t)
{
    const int tensor = blk / 100;         // 0 = q, 1 = s
    const int tile   = blk % 100;         // b*25 + i (or j)
    const float* src = (tensor ? s : q) + (size_t)tile * 8192;
    u16*         dst = ws + (size_t)blk * 8192;

    const int row  = t >> 1;              // pair (t, t^1) shares a row
    const int half = t & 1;               // == ks
    const float* gp = src + row * 64 + half * 32;

    float4 f[8];
#pragma unroll
    for (int c = 0; c < 8; ++c) f[c] = ((const float4*)gp)[c];
    float ss = 0.f;
#pragma unroll
    for (int c = 0; c < 8; ++c)
        ss += f[c].x*f[c].x + f[c].y*f[c].y + f[c].z*f[c].z + f[c].w*f[c].w;
    ss += __shfl_xor(ss, 1);                          // full-row sumsq
    const float r = 1.0f / fmaxf(sqrtf(ss), 1e-12f);  // torch F.normalize eps

    u16* base = dst + ((size_t)((row >> 4) * 2 + half) * 512) + (row & 15) * 8;
#pragma unroll
    for (int c = 0; c < 4; ++c) {
        uint4v pk;
        pk.x = pack2bf(f[2*c].x * r,   f[2*c].y * r);
        pk.y = pack2bf(f[2*c].z * r,   f[2*c].w * r);
        pk.z = pack2bf(f[2*c+1].x * r, f[2*c+1].y * r);
        pk.w = pack2bf(f[2*c+1].z * r, f[2*c+1].w * r);
        *(uint4v*)(base + c * 128) = pk;
    }
}

struct Frags { short8 a[2][4]; short8 b[2][4]; };   // 64 VGPRs

__device__ __forceinline__ void load_frags(Frags& F, const u16* __restrict__ ws,
                                           int tidx, int m0, int n0, int lane)
{
    const int b   = tidx / 625;
    const int rem = tidx % 625;
    const int i   = rem / 25;
    const int j   = rem % 25;
    const u16* qt = ws + (size_t)(b * 25 + i) * 8192;
    const u16* st = ws + (size_t)(100 + b * 25 + j) * 8192;
#pragma unroll
    for (int ks = 0; ks < 2; ++ks) {
#pragma unroll
        for (int mt = 0; mt < 4; ++mt)
            F.a[ks][mt] = *(const short8*)(qt +
                          (size_t)(((m0 >> 4) + mt) * 2 + ks) * 512 + lane * 8);
#pragma unroll
        for (int nt = 0; nt < 4; ++nt)
            F.b[ks][nt] = *(const short8*)(st +
                          (size_t)(((n0 >> 4) + nt) * 2 + ks) * 512 + lane * 8);
    }
}

__device__ __forceinline__ void store_tile(float* __restrict__ out, int tidx,
                                           const floatx4 acc[4][4],
                                           int m0, int n0, int quad, int l15)
{
    // MFMA C/D layout (probe-verified): row = quad*4 + r, col = l15.
    float* obase = out + (size_t)tidx * 16384 + n0 + l15;
#pragma unroll
    for (int mt = 0; mt < 4; ++mt)
#pragma unroll
        for (int r = 0; r < 4; ++r) {
            float* op = obase + (size_t)(m0 + mt * 16 + quad * 4 + r) * 128;
#pragma unroll
            for (int nt = 0; nt < 4; ++nt)
                op[nt * 16] = acc[mt][nt][r];
        }
}

// ---------------------------------------------------------------------------
// Fused cooperative persistent kernel. Grid = 512 blocks, all co-resident
// (launch_bounds(256,2) -> <=256 VGPR -> 2 blocks/CU x 256 CU = 512).
//   Phase 1: blocks 0..199 normalize one tile each into ws.
//   grid.sync()  (device-scope fences included; + explicit threadfence)
//   Phase 2: grid-stride over 2500 output tiles (~5/block), with next-tile
//   fragment PREFETCH issued before the current tile's stores so the read
//   latency hides under the store stream. No LDS, no __syncthreads.
// ---------------------------------------------------------------------------
__global__ __launch_bounds__(256, 2)
void fused_cosine_kernel(const float* __restrict__ q,
                         const float* __restrict__ s,
                         u16* __restrict__ ws,
                         float* __restrict__ out)
{
    const int blk = blockIdx.x;
    const int t   = threadIdx.x;

    if (blk < 200) normalize_tile(q, s, ws, blk, t);
    __threadfence();                     // device-scope release of ws writes
    cg::this_grid().sync();

    const int wave = t >> 6;
    const int lane = t & 63;
    const int quad = lane >> 4;
    const int l15  = lane & 15;
    const int m0   = (wave >> 1) * 64;
    const int n0   = (wave & 1) * 64;

    Frags cur;
    load_frags(cur, ws, blk, m0, n0, lane);   // blk < 512 < 2500 always valid

#pragma unroll
    for (int it = 0; it < 5; ++it) {
        const int tc = blk + it * 512;
        if (tc >= 2500) break;
        floatx4 acc[4][4] = {};
#pragma unroll
        for (int ks = 0; ks < 2; ++ks)
#pragma unroll
            for (int mt = 0; mt < 4; ++mt)
#pragma unroll
                for (int nt = 0; nt < 4; ++nt)
                    acc[mt][nt] = __builtin_amdgcn_mfma_f32_16x16x32_bf16(
                        cur.a[ks][mt], cur.b[ks][nt], acc[mt][nt], 0, 0, 0);
        const int tn = tc + 512;
        Frags nxt;
        if (tn < 2500) load_frags(nxt, ws, tn, m0, n0, lane);  // prefetch
        store_tile(out, tc, acc, m0, n0, quad, l15);
        if (tn < 2500) cur = nxt;
    }
}

// ---------------------------------------------------------------------------
// Fallback A: round-1 verified two-kernel split (169 us).
// ---------------------------------------------------------------------------
__global__ __launch_bounds__(256)
void normalize_pack_kernel(const float* __restrict__ q,
                           const float* __restrict__ s,
                           u16* __restrict__ ws)
{
    normalize_tile(q, s, ws, blockIdx.x, threadIdx.x);
}

__global__ __launch_bounds__(256, 4)
void cosine_gemm_kernel(const u16* __restrict__ ws,
                        float* __restrict__ out)
{
    const int t   = threadIdx.x;
    const int blk = blockIdx.x;
    const int wave = t >> 6;
    const int lane = t & 63;
    const int quad = lane >> 4;
    const int l15  = lane & 15;
    const int m0   = (wave >> 1) * 64;
    const int n0   = (wave & 1) * 64;

    Frags F;
    load_frags(F, ws, blk, m0, n0, lane);
    floatx4 acc[4][4] = {};
#pragma unroll
    for (int ks = 0; ks < 2; ++ks)
#pragma unroll
        for (int mt = 0; mt < 4; ++mt)
#pragma unroll
            for (int nt = 0; nt < 4; ++nt)
                acc[mt][nt] = __builtin_amdgcn_mfma_f32_16x16x32_bf16(
                    F.a[ks][mt], F.b[ks][nt], acc[mt][nt], 0, 0, 0);
    store_tile(out, blk, acc, m0, n0, quad, l15);
}

// ---------------------------------------------------------------------------
// Fallback B: original verified single kernel (used if ws too small).
// ---------------------------------------------------------------------------
#define QPITCH 72

__global__ __launch_bounds__(256, 4)
void cosine_relation_kernel(const float* __restrict__ q,
                            const float* __restrict__ s,
                            float* __restrict__ out)
{
    __shared__ u16 smem[2 * 128 * QPITCH];
    u16* qt = smem;
    u16* st = smem + 128 * QPITCH;

    const int t   = threadIdx.x;
    const int blk = blockIdx.x;
    const int b   = blk / 625;
    const int rem = blk % 625;
    const int i   = rem / 25;
    const int j   = rem % 25;

    const float* qbase = q + (size_t)(b * 25 + i) * 8192;
    const float* sbase = s + (size_t)(b * 25 + j) * 8192;

    const int row  = t >> 1;
    const int half = t & 1;
#pragma unroll
    for (int tile = 0; tile < 2; ++tile) {
        const float* gp = (tile == 0 ? qbase : sbase) + row * 64 + half * 32;
        u16*         lp = (tile == 0 ? qt : st) + row * QPITCH + half * 32;
        float4 f[8];
#pragma unroll
        for (int c = 0; c < 8; ++c) f[c] = ((const float4*)gp)[c];
        float ss = 0.f;
#pragma unroll
        for (int c = 0; c < 8; ++c)
            ss += f[c].x*f[c].x + f[c].y*f[c].y + f[c].z*f[c].z + f[c].w*f[c].w;
        ss += __shfl_xor(ss, 1);
        const float r = 1.0f / fmaxf(sqrtf(ss), 1e-12f);
#pragma unroll
        for (int c = 0; c < 4; ++c) {
            uint4v pk;
            pk.x = pack2bf(f[2*c].x * r,   f[2*c].y * r);
            pk.y = pack2bf(f[2*c].z * r,   f[2*c].w * r);
            pk.z = pack2bf(f[2*c+1].x * r, f[2*c+1].y * r);
            pk.w = pack2bf(f[2*c+1].z * r, f[2*c+1].w * r);
            *(uint4v*)(lp + c * 8) = pk;
        }
    }
    __syncthreads();

    const int wave = t >> 6;
    const int lane = t & 63;
    const int quad = lane >> 4;
    const int l15  = lane & 15;
    const int m0   = (wave >> 1) * 64;
    const int n0   = (wave & 1) * 64;

    floatx4 acc[4][4] = {};
#pragma unroll
    for (int ks = 0; ks < 2; ++ks) {
        short8 af[4], bfr[4];
#pragma unroll
        for (int mt = 0; mt < 4; ++mt)
            af[mt] = *(const short8*)(qt + (m0 + mt * 16 + l15) * QPITCH + ks * 32 + quad * 8);
#pragma unroll
        for (int nt = 0; nt < 4; ++nt)
            bfr[nt] = *(const short8*)(st + (n0 + nt * 16 + l15) * QPITCH + ks * 32 + quad * 8);
#pragma unroll
        for (int mt = 0; mt < 4; ++mt)
#pragma unroll
            for (int nt = 0; nt < 4; ++nt)
                acc[mt][nt] = __builtin_amdgcn_mfma_f32_16x16x32_bf16(
                    af[mt], bfr[nt], acc[mt][nt], 0, 0, 0);
    }

    float* obase = out + (size_t)blk * 16384 + n0 + l15;
#pragma unroll
    for (int mt = 0; mt < 4; ++mt)
#pragma unroll
        for (int r = 0; r < 4; ++r) {
            float* op = obase + (size_t)(m0 + mt * 16 + quad * 4 + r) * 128;
#pragma unroll
            for (int nt = 0; nt < 4; ++nt)
                op[nt * 16] = acc[mt][nt][r];
        }
}

extern "C" void kernel_launch(void* const* d_in, const int* in_sizes, int n_in,
                              void* d_out, int out_size, void* d_ws, size_t ws_size,
                              hipStream_t stream) {
    const float* q = (const float*)d_in[0];
    const float* s = (const float*)d_in[1];
    float* out = (float*)d_out;

    const size_t WS_NEED = (size_t)200 * 16384;   // 3.2 MB bf16 workspace
    if (d_ws != nullptr && ws_size >= WS_NEED) {
        u16* ws = (u16*)d_ws;
        void* args[] = { (void*)&q, (void*)&s, (void*)&ws, (void*)&out };
        hipError_t e = hipLaunchCooperativeKernel(
            (const void*)fused_cosine_kernel, dim3(512), dim3(256),
            args, 0, stream);
        if (e == hipSuccess) return;
        (void)hipGetLastError();          // clear error state, fall back
        normalize_pack_kernel<<<200, 256, 0, stream>>>(q, s, ws);
        cosine_gemm_kernel<<<2500, 256, 0, stream>>>(ws, out);
    } else {
        cosine_relation_kernel<<<2500, 256, 0, stream>>>(q, s, out);
    }
}

// Round 5
// 170.789 us; speedup vs baseline: 1.7238x; 1.7238x over previous
//
#include <hip/hip_runtime.h>

typedef unsigned short u16;
typedef unsigned int u32;
typedef __attribute__((ext_vector_type(8))) short short8;    // 8 bf16 (4 VGPRs)
typedef __attribute__((ext_vector_type(4))) float floatx4;   // 4 fp32 acc
typedef __attribute__((ext_vector_type(4))) u32 uint4v;

// Pack two fp32 -> two bf16 (RNE) in one dword: low16=bf(a), high16=bf(b).
__device__ __forceinline__ u32 pack2bf(float a, float b) {
    u32 ua = __float_as_uint(a), ub = __float_as_uint(b);
    ua += 0x7fffu + ((ua >> 16) & 1u);   // RNE
    ub += 0x7fffu + ((ub >> 16) & 1u);
    return __builtin_amdgcn_perm(ub, ua, 0x07060302);
}

// ---------------------------------------------------------------------------
// Kernel N: L2-normalize each 128x64 tile ONCE (200 tiles: 100 q + 100 s),
// pack to bf16, store to ws in MFMA-FRAGMENT ORDER:
//   elem addr(rowblk, ks, lane) = blk*8192 + (rowblk*2 + ks)*512 + lane*8
// lane = quad*16 + l15 holds elems [ks*32 + quad*8 .. +8) of row rowblk*16+l15,
// so a GEMM fragment load is one coalesced global_load_dwordx4 (1 KB/wave).
// ---------------------------------------------------------------------------
__global__ __launch_bounds__(256)
void normalize_pack_kernel(const float* __restrict__ q,
                           const float* __restrict__ s,
                           u16* __restrict__ ws)
{
    const int t      = threadIdx.x;
    const int blk    = blockIdx.x;        // 0..199
    const int tensor = blk / 100;         // 0 = q, 1 = s
    const int tile   = blk % 100;         // b*25 + i (or j)

    const float* src = (tensor ? s : q) + (size_t)tile * 8192;   // 128x64 fp32
    u16*         dst = ws + (size_t)blk * 8192;                  // 16 KB bf16

    const int row  = t >> 1;              // pair (t, t^1) shares a row
    const int half = t & 1;               // == ks
    const float* gp = src + row * 64 + half * 32;

    float4 f[8];
#pragma unroll
    for (int c = 0; c < 8; ++c) f[c] = ((const float4*)gp)[c];
    float ss = 0.f;
#pragma unroll
    for (int c = 0; c < 8; ++c)
        ss += f[c].x*f[c].x + f[c].y*f[c].y + f[c].z*f[c].z + f[c].w*f[c].w;
    ss += __shfl_xor(ss, 1);                          // full-row sumsq
    const float r = 1.0f / fmaxf(sqrtf(ss), 1e-12f);  // torch F.normalize eps

    u16* base = dst + ((size_t)((row >> 4) * 2 + half) * 512) + (row & 15) * 8;
#pragma unroll
    for (int c = 0; c < 4; ++c) {
        uint4v pk;
        pk.x = pack2bf(f[2*c].x * r,   f[2*c].y * r);
        pk.y = pack2bf(f[2*c].z * r,   f[2*c].w * r);
        pk.z = pack2bf(f[2*c+1].x * r, f[2*c+1].y * r);
        pk.w = pack2bf(f[2*c+1].z * r, f[2*c+1].w * r);
        *(uint4v*)(base + c * 128) = pk;
    }
}

// ---------------------------------------------------------------------------
// Kernel G: MFMA with SWAPPED operands so the accumulator register axis runs
// along n (contiguous output dim):
//   acc[mt][nt] = mfma(s_frag[nt], q_frag[mt], acc)  ->  D'[n][m]
//   lane (quad,l15), reg r: n = n0 + nt*16 + quad*4 + r, m = m0 + mt*16 + l15
// => each floatx4 acc frag is 16 B of consecutive out memory -> epilogue is
// 16 global_store_dwordx4 per wave (1 KB/instr), no LDS, no transpose.
// Per-ks fragment loading keeps peak VGPR ~110 -> fits (256,4) = 16 waves/CU.
// ---------------------------------------------------------------------------
__global__ __launch_bounds__(256, 4)
void cosine_gemm_kernel(const u16* __restrict__ ws,
                        float* __restrict__ out)
{
    const int t   = threadIdx.x;
    const int blk = blockIdx.x;           // == (b*25 + i)*25 + j
    const int b   = blk / 625;
    const int rem = blk % 625;
    const int i   = rem / 25;
    const int j   = rem % 25;

    const u16* qt = ws + (size_t)(b * 25 + i) * 8192;
    const u16* st = ws + (size_t)(100 + b * 25 + j) * 8192;

    const int wave = t >> 6;
    const int lane = t & 63;
    const int quad = lane >> 4;
    const int l15  = lane & 15;
    const int m0   = (wave >> 1) * 64;
    const int n0   = (wave & 1) * 64;

    floatx4 acc[4][4] = {};               // acc[mt][nt]: rows=n, cols=m
#pragma unroll
    for (int ks = 0; ks < 2; ++ks) {
        short8 a[4], bfr[4];              // only 32 VGPRs live
#pragma unroll
        for (int mt = 0; mt < 4; ++mt)
            a[mt] = *(const short8*)(qt +
                    (size_t)(((m0 >> 4) + mt) * 2 + ks) * 512 + lane * 8);
#pragma unroll
        for (int nt = 0; nt < 4; ++nt)
            bfr[nt] = *(const short8*)(st +
                    (size_t)(((n0 >> 4) + nt) * 2 + ks) * 512 + lane * 8);
#pragma unroll
        for (int mt = 0; mt < 4; ++mt)
#pragma unroll
            for (int nt = 0; nt < 4; ++nt)
                acc[mt][nt] = __builtin_amdgcn_mfma_f32_16x16x32_bf16(
                    bfr[nt], a[mt], acc[mt][nt], 0, 0, 0);   // SWAPPED A<->B
    }

    // out[m][n]: m = m0 + mt*16 + l15, n = n0 + nt*16 + quad*4 + {0..3}
    float* obase = out + (size_t)blk * 16384
                       + (size_t)(m0 + l15) * 128 + n0 + quad * 4;
#pragma unroll
    for (int mt = 0; mt < 4; ++mt) {
        float* orow = obase + (size_t)mt * 16 * 128;
#pragma unroll
        for (int nt = 0; nt < 4; ++nt)
            *(floatx4*)(orow + nt * 16) = acc[mt][nt];
    }
}

// ---------------------------------------------------------------------------
// Fallback: original verified single kernel (used if ws too small).
// ---------------------------------------------------------------------------
#define QPITCH 72

__global__ __launch_bounds__(256, 4)
void cosine_relation_kernel(const float* __restrict__ q,
                            const float* __restrict__ s,
                            float* __restrict__ out)
{
    __shared__ u16 smem[2 * 128 * QPITCH];
    u16* qt = smem;
    u16* st = smem + 128 * QPITCH;

    const int t   = threadIdx.x;
    const int blk = blockIdx.x;
    const int b   = blk / 625;
    const int rem = blk % 625;
    const int i   = rem / 25;
    const int j   = rem % 25;

    const float* qbase = q + (size_t)(b * 25 + i) * 8192;
    const float* sbase = s + (size_t)(b * 25 + j) * 8192;

    const int row  = t >> 1;
    const int half = t & 1;
#pragma unroll
    for (int tile = 0; tile < 2; ++tile) {
        const float* gp = (tile == 0 ? qbase : sbase) + row * 64 + half * 32;
        u16*         lp = (tile == 0 ? qt : st) + row * QPITCH + half * 32;
        float4 f[8];
#pragma unroll
        for (int c = 0; c < 8; ++c) f[c] = ((const float4*)gp)[c];
        float ss = 0.f;
#pragma unroll
        for (int c = 0; c < 8; ++c)
            ss += f[c].x*f[c].x + f[c].y*f[c].y + f[c].z*f[c].z + f[c].w*f[c].w;
        ss += __shfl_xor(ss, 1);
        const float r = 1.0f / fmaxf(sqrtf(ss), 1e-12f);
#pragma unroll
        for (int c = 0; c < 4; ++c) {
            uint4v pk;
            pk.x = pack2bf(f[2*c].x * r,   f[2*c].y * r);
            pk.y = pack2bf(f[2*c].z * r,   f[2*c].w * r);
            pk.z = pack2bf(f[2*c+1].x * r, f[2*c+1].y * r);
            pk.w = pack2bf(f[2*c+1].z * r, f[2*c+1].w * r);
            *(uint4v*)(lp + c * 8) = pk;
        }
    }
    __syncthreads();

    const int wave = t >> 6;
    const int lane = t & 63;
    const int quad = lane >> 4;
    const int l15  = lane & 15;
    const int m0   = (wave >> 1) * 64;
    const int n0   = (wave & 1) * 64;

    floatx4 acc[4][4] = {};
#pragma unroll
    for (int ks = 0; ks < 2; ++ks) {
        short8 af[4], bfr[4];
#pragma unroll
        for (int mt = 0; mt < 4; ++mt)
            af[mt] = *(const short8*)(qt + (m0 + mt * 16 + l15) * QPITCH + ks * 32 + quad * 8);
#pragma unroll
        for (int nt = 0; nt < 4; ++nt)
            bfr[nt] = *(const short8*)(st + (n0 + nt * 16 + l15) * QPITCH + ks * 32 + quad * 8);
#pragma unroll
        for (int mt = 0; mt < 4; ++mt)
#pragma unroll
            for (int nt = 0; nt < 4; ++nt)
                acc[mt][nt] = __builtin_amdgcn_mfma_f32_16x16x32_bf16(
                    af[mt], bfr[nt], acc[mt][nt], 0, 0, 0);
    }

    float* obase = out + (size_t)blk * 16384 + n0 + l15;
#pragma unroll
    for (int mt = 0; mt < 4; ++mt)
#pragma unroll
        for (int r = 0; r < 4; ++r) {
            float* op = obase + (size_t)(m0 + mt * 16 + quad * 4 + r) * 128;
#pragma unroll
            for (int nt = 0; nt < 4; ++nt)
                op[nt * 16] = acc[mt][nt][r];
        }
}

extern "C" void kernel_launch(void* const* d_in, const int* in_sizes, int n_in,
                              void* d_out, int out_size, void* d_ws, size_t ws_size,
                              hipStream_t stream) {
    const float* q = (const float*)d_in[0];
    const float* s = (const float*)d_in[1];
    float* out = (float*)d_out;

    const size_t WS_NEED = (size_t)200 * 16384;   // 3.2 MB bf16 workspace
    if (d_ws != nullptr && ws_size >= WS_NEED) {
        u16* ws = (u16*)d_ws;
        normalize_pack_kernel<<<200, 256, 0, stream>>>(q, s, ws);
        cosine_gemm_kernel<<<2500, 256, 0, stream>>>(ws, out);
    } else {
        cosine_relation_kernel<<<2500, 256, 0, stream>>>(q, s, out);
    }
}

// Round 6
// 168.525 us; speedup vs baseline: 1.7469x; 1.0134x over previous
//
#include <hip/hip_runtime.h>

typedef unsigned short u16;
typedef unsigned int u32;
typedef __attribute__((ext_vector_type(8))) short short8;    // 8 bf16 (4 VGPRs)
typedef __attribute__((ext_vector_type(4))) float floatx4;   // 4 fp32 acc
typedef __attribute__((ext_vector_type(4))) u32 uint4v;

// Pack two fp32 -> two bf16 (RNE) in one dword: low16=bf(a), high16=bf(b).
__device__ __forceinline__ u32 pack2bf(float a, float b) {
    u32 ua = __float_as_uint(a), ub = __float_as_uint(b);
    ua += 0x7fffu + ((ua >> 16) & 1u);   // RNE
    ub += 0x7fffu + ((ub >> 16) & 1u);
    return __builtin_amdgcn_perm(ub, ua, 0x07060302);
}

// ---------------------------------------------------------------------------
// Kernel N: L2-normalize each 128x64 tile ONCE (200 tiles: 100 q + 100 s),
// pack to bf16, store to ws in MFMA-FRAGMENT ORDER:
//   elem addr(rowblk, ks, lane) = blk*8192 + (rowblk*2 + ks)*512 + lane*8
// lane = quad*16 + l15 holds elems [ks*32 + quad*8 .. +8) of row rowblk*16+l15,
// so a GEMM fragment load is one coalesced global_load_dwordx4 (1 KB/wave).
// ---------------------------------------------------------------------------
__global__ __launch_bounds__(256)
void normalize_pack_kernel(const float* __restrict__ q,
                           const float* __restrict__ s,
                           u16* __restrict__ ws)
{
    const int t      = threadIdx.x;
    const int blk    = blockIdx.x;        // 0..199
    const int tensor = blk / 100;         // 0 = q, 1 = s
    const int tile   = blk % 100;         // b*25 + i (or j)

    const float* src = (tensor ? s : q) + (size_t)tile * 8192;   // 128x64 fp32
    u16*         dst = ws + (size_t)blk * 8192;                  // 16 KB bf16

    const int row  = t >> 1;              // pair (t, t^1) shares a row
    const int half = t & 1;               // == ks
    const float* gp = src + row * 64 + half * 32;

    float4 f[8];
#pragma unroll
    for (int c = 0; c < 8; ++c) f[c] = ((const float4*)gp)[c];
    float ss = 0.f;
#pragma unroll
    for (int c = 0; c < 8; ++c)
        ss += f[c].x*f[c].x + f[c].y*f[c].y + f[c].z*f[c].z + f[c].w*f[c].w;
    ss += __shfl_xor(ss, 1);                          // full-row sumsq
    const float r = 1.0f / fmaxf(sqrtf(ss), 1e-12f);  // torch F.normalize eps

    u16* base = dst + ((size_t)((row >> 4) * 2 + half) * 512) + (row & 15) * 8;
#pragma unroll
    for (int c = 0; c < 4; ++c) {
        uint4v pk;
        pk.x = pack2bf(f[2*c].x * r,   f[2*c].y * r);
        pk.y = pack2bf(f[2*c].z * r,   f[2*c].w * r);
        pk.z = pack2bf(f[2*c+1].x * r, f[2*c+1].y * r);
        pk.w = pack2bf(f[2*c+1].z * r, f[2*c+1].w * r);
        *(uint4v*)(base + c * 128) = pk;
    }
}

// ---------------------------------------------------------------------------
// Kernel G: ONE WAVE PER BLOCK (64x64 output quadrant), 10,000 blocks.
// Rationale (r5 post-mortem): store BW needs a CONTINUOUS store stream per
// CU; 4-wave blocks hit their load/MFMA/store phases in lockstep -> bursty
// stores, ~2.7 TB/s. 16 independent 1-wave blocks per CU (launch_bounds
// (64,4): 4 waves/SIMD, VGPR cap 128 >= ~110 used) sit at staggered phases,
// so some wave is always issuing stores.
// MFMA operands SWAPPED so acc register axis runs along n (contiguous out):
//   acc[mt][nt] = mfma(s_frag[nt], q_frag[mt], acc)
//   lane (quad,l15), reg r: n = n0 + nt*16 + quad*4 + r, m = m0 + mt*16 + l15
// -> each floatx4 acc frag is 16 B of consecutive out memory -> 16
// global_store_dwordx4 per wave, no LDS, no transpose.
// ---------------------------------------------------------------------------
__global__ __launch_bounds__(64, 4)
void cosine_gemm_kernel(const u16* __restrict__ ws,
                        float* __restrict__ out)
{
    const int lane = threadIdx.x;         // 0..63 (one full wave)
    const int blk  = blockIdx.x;          // 0..9999
    const int tile = blk >> 2;            // == (b*25 + i)*25 + j
    const int wq   = blk & 3;             // output quadrant
    const int b    = tile / 625;
    const int rem  = tile % 625;
    const int i    = rem / 25;
    const int j    = rem % 25;

    const u16* qt = ws + (size_t)(b * 25 + i) * 8192;
    const u16* st = ws + (size_t)(100 + b * 25 + j) * 8192;

    const int quad = lane >> 4;
    const int l15  = lane & 15;
    const int m0   = (wq >> 1) * 64;
    const int n0   = (wq & 1) * 64;

    floatx4 acc[4][4] = {};               // acc[mt][nt]: reg axis = n
#pragma unroll
    for (int ks = 0; ks < 2; ++ks) {
        short8 a[4], bfr[4];              // only 32 VGPRs live
#pragma unroll
        for (int mt = 0; mt < 4; ++mt)
            a[mt] = *(const short8*)(qt +
                    (size_t)(((m0 >> 4) + mt) * 2 + ks) * 512 + lane * 8);
#pragma unroll
        for (int nt = 0; nt < 4; ++nt)
            bfr[nt] = *(const short8*)(st +
                    (size_t)(((n0 >> 4) + nt) * 2 + ks) * 512 + lane * 8);
#pragma unroll
        for (int mt = 0; mt < 4; ++mt)
#pragma unroll
            for (int nt = 0; nt < 4; ++nt)
                acc[mt][nt] = __builtin_amdgcn_mfma_f32_16x16x32_bf16(
                    bfr[nt], a[mt], acc[mt][nt], 0, 0, 0);   // SWAPPED A<->B
    }

    // out[m][n]: m = m0 + mt*16 + l15, n = n0 + nt*16 + quad*4 + {0..3}
    float* obase = out + (size_t)tile * 16384
                       + (size_t)(m0 + l15) * 128 + n0 + quad * 4;
#pragma unroll
    for (int mt = 0; mt < 4; ++mt) {
        float* orow = obase + (size_t)mt * 16 * 128;
#pragma unroll
        for (int nt = 0; nt < 4; ++nt)
            *(floatx4*)(orow + nt * 16) = acc[mt][nt];
    }
}

// ---------------------------------------------------------------------------
// Fallback: original verified single kernel (used if ws too small).
// ---------------------------------------------------------------------------
#define QPITCH 72

__global__ __launch_bounds__(256, 4)
void cosine_relation_kernel(const float* __restrict__ q,
                            const float* __restrict__ s,
                            float* __restrict__ out)
{
    __shared__ u16 smem[2 * 128 * QPITCH];
    u16* qt = smem;
    u16* st = smem + 128 * QPITCH;

    const int t   = threadIdx.x;
    const int blk = blockIdx.x;
    const int b   = blk / 625;
    const int rem = blk % 625;
    const int i   = rem / 25;
    const int j   = rem % 25;

    const float* qbase = q + (size_t)(b * 25 + i) * 8192;
    const float* sbase = s + (size_t)(b * 25 + j) * 8192;

    const int row  = t >> 1;
    const int half = t & 1;
#pragma unroll
    for (int tile = 0; tile < 2; ++tile) {
        const float* gp = (tile == 0 ? qbase : sbase) + row * 64 + half * 32;
        u16*         lp = (tile == 0 ? qt : st) + row * QPITCH + half * 32;
        float4 f[8];
#pragma unroll
        for (int c = 0; c < 8; ++c) f[c] = ((const float4*)gp)[c];
        float ss = 0.f;
#pragma unroll
        for (int c = 0; c < 8; ++c)
            ss += f[c].x*f[c].x + f[c].y*f[c].y + f[c].z*f[c].z + f[c].w*f[c].w;
        ss += __shfl_xor(ss, 1);
        const float r = 1.0f / fmaxf(sqrtf(ss), 1e-12f);
#pragma unroll
        for (int c = 0; c < 4; ++c) {
            uint4v pk;
            pk.x = pack2bf(f[2*c].x * r,   f[2*c].y * r);
            pk.y = pack2bf(f[2*c].z * r,   f[2*c].w * r);
            pk.z = pack2bf(f[2*c+1].x * r, f[2*c+1].y * r);
            pk.w = pack2bf(f[2*c+1].z * r, f[2*c+1].w * r);
            *(uint4v*)(lp + c * 8) = pk;
        }
    }
    __syncthreads();

    const int wave = t >> 6;
    const int lane = t & 63;
    const int quad = lane >> 4;
    const int l15  = lane & 15;
    const int m0   = (wave >> 1) * 64;
    const int n0   = (wave & 1) * 64;

    floatx4 acc[4][4] = {};
#pragma unroll
    for (int ks = 0; ks < 2; ++ks) {
        short8 af[4], bfr[4];
#pragma unroll
        for (int mt = 0; mt < 4; ++mt)
            af[mt] = *(const short8*)(qt + (m0 + mt * 16 + l15) * QPITCH + ks * 32 + quad * 8);
#pragma unroll
        for (int nt = 0; nt < 4; ++nt)
            bfr[nt] = *(const short8*)(st + (n0 + nt * 16 + l15) * QPITCH + ks * 32 + quad * 8);
#pragma unroll
        for (int mt = 0; mt < 4; ++mt)
#pragma unroll
            for (int nt = 0; nt < 4; ++nt)
                acc[mt][nt] = __builtin_amdgcn_mfma_f32_16x16x32_bf16(
                    af[mt], bfr[nt], acc[mt][nt], 0, 0, 0);
    }

    float* obase = out + (size_t)blk * 16384 + n0 + l15;
#pragma unroll
    for (int mt = 0; mt < 4; ++mt)
#pragma unroll
        for (int r = 0; r < 4; ++r) {
            float* op = obase + (size_t)(m0 + mt * 16 + quad * 4 + r) * 128;
#pragma unroll
            for (int nt = 0; nt < 4; ++nt)
                op[nt * 16] = acc[mt][nt][r];
        }
}

extern "C" void kernel_launch(void* const* d_in, const int* in_sizes, int n_in,
                              void* d_out, int out_size, void* d_ws, size_t ws_size,
                              hipStream_t stream) {
    const float* q = (const float*)d_in[0];
    const float* s = (const float*)d_in[1];
    float* out = (float*)d_out;

    const size_t WS_NEED = (size_t)200 * 16384;   // 3.2 MB bf16 workspace
    if (d_ws != nullptr && ws_size >= WS_NEED) {
        u16* ws = (u16*)d_ws;
        normalize_pack_kernel<<<200, 256, 0, stream>>>(q, s, ws);
        cosine_gemm_kernel<<<10000, 64, 0, stream>>>(ws, out);
    } else {
        cosine_relation_kernel<<<2500, 256, 0, stream>>>(q, s, out);
    }
}